// Round 4
// baseline (954.173 us; speedup 1.0000x reference)
//
#include <hip/hip_runtime.h>

// VQ-VAE quantize, BIT-EXACT replication of the numpy float32 reference:
//   sumx = np.sum(xf*xf, axis=1)   [numpy pairwise_sum, n=64, 8-accumulator order]
//   sume = np.sum(emb*emb, axis=1) [same]
//   M    = (2.0*xf) @ emb.T        [OpenBLAS sgemm: sequential k-order FMA, beta=0]
//   d    = fl32(fl32(sumx + sume) - M);  idx = argmin (first minimum)
//
// R3: passed, absmax=0, 621 us. Occupancy 23.7% (grid 512 blocks = 2/CU),
// VALUBusy 39% -> latency-bound on emb s_loads. This version k-splits x4:
// block = 4 waves x 64 rows, wave `seg` covers k in [seg*256, seg*256+256).
// Grid 512 -> 2048 blocks (8/CU). Dot products bit-identical (same i-order FMA);
// argmin combined across segs in LDS by ascending seg with strict < (= np first-min).

#define N_ROWS   131072
#define NUM_EMB  1024
#define EMB_DIM  64
#define Q_ELEMS  8388608
#define KSEG     256          // k per wave-segment
#define ROWS_PB  64           // rows per block

// numpy pairwise_sum (n=64, contiguous) of fl32(a[i]*a[i]).
__device__ __forceinline__ float np_pairwise_sq64(const float* a) {
    #pragma clang fp contract(off)
    float r0 = a[0]*a[0], r1 = a[1]*a[1], r2 = a[2]*a[2], r3 = a[3]*a[3];
    float r4 = a[4]*a[4], r5 = a[5]*a[5], r6 = a[6]*a[6], r7 = a[7]*a[7];
    #pragma unroll
    for (int i = 8; i < 64; i += 8) {
        r0 += a[i+0]*a[i+0];
        r1 += a[i+1]*a[i+1];
        r2 += a[i+2]*a[i+2];
        r3 += a[i+3]*a[i+3];
        r4 += a[i+4]*a[i+4];
        r5 += a[i+5]*a[i+5];
        r6 += a[i+6]*a[i+6];
        r7 += a[i+7]*a[i+7];
    }
    return ((r0 + r1) + (r2 + r3)) + ((r4 + r5) + (r6 + r7));
}

__global__ __launch_bounds__(256) void vq_prep(const float* __restrict__ emb,
                                               float* __restrict__ sume) {
    int k = blockIdx.x * 256 + threadIdx.x;
    if (k < NUM_EMB) {
        sume[k] = np_pairwise_sq64(emb + (k << 6));
    }
}

__global__ __launch_bounds__(256) void vq_main(const float* __restrict__ x,
                                               const float* __restrict__ emb,
                                               const float* __restrict__ sume,
                                               float* __restrict__ out_q,
                                               float* __restrict__ out_idx) {
    const int t    = threadIdx.x;
    const int seg  = t >> 6;            // wave index = k-segment (wave-uniform)
    const int r    = t & 63;            // row within block
    const int row  = blockIdx.x * ROWS_PB + r;
    const int kbeg = seg * KSEG;

    // Load this thread's 64-float row into registers (4 segs share a row -> L1 hits).
    float rx[EMB_DIM];
    const float4* xr = reinterpret_cast<const float4*>(x + (size_t)row * EMB_DIM);
    #pragma unroll
    for (int j = 0; j < 16; ++j) {
        float4 v = xr[j];
        rx[4*j+0] = v.x; rx[4*j+1] = v.y; rx[4*j+2] = v.z; rx[4*j+3] = v.w;
    }

    // numpy-order fl32 sum of squares, then scale row by 2 (exact, matches 2.0*xf).
    const float sumx = np_pairwise_sq64(rx);
    #pragma unroll
    for (int i = 0; i < EMB_DIM; ++i) rx[i] *= 2.0f;

    float m = 3.4e38f;
    int   b = 0;

    // Segment k-loop: sgemm-order sequential-k FMA, 2 independent chains for ILP.
    for (int k = kbeg; k < kbeg + KSEG; k += 2) {
        const float* __restrict__ e0 = emb + (k << 6);   // wave-uniform -> s_load
        float c0 = 0.0f, c1 = 0.0f;
        #pragma unroll
        for (int i = 0; i < EMB_DIM; ++i) {
            c0 = fmaf(rx[i], e0[i],      c0);
            c1 = fmaf(rx[i], e0[64 + i], c1);
        }
        {
            #pragma clang fp contract(off)
            float t0 = sumx + sume[k];     // fl32 add at magnitude ~64
            float d0 = t0 - c0;            // fl32 sub -> the decisive grid rounding
            float t1 = sumx + sume[k + 1];
            float d1 = t1 - c1;
            if (d0 < m) { m = d0; b = k; }     // strict < => first-min (np.argmin)
            if (d1 < m) { m = d1; b = k + 1; }
        }
    }

    // Combine the 4 segment-partials per row: ascending seg, strict < keeps the
    // lowest-k winner on ties -> exact np.argmin first-min semantics.
    __shared__ float lm[4][ROWS_PB];
    __shared__ int   lb[4][ROWS_PB];
    __shared__ int   sidx[ROWS_PB];
    lm[seg][r] = m;
    lb[seg][r] = b;
    __syncthreads();
    if (t < ROWS_PB) {
        float bm = lm[0][t]; int bb = lb[0][t];
        #pragma unroll
        for (int s = 1; s < 4; ++s) {
            float sm = lm[s][t];
            if (sm < bm) { bm = sm; bb = lb[s][t]; }
        }
        out_idx[blockIdx.x * ROWS_PB + t] = (float)bb;
        sidx[t] = bb;
    }
    __syncthreads();

    // Cooperative coalesced gather: quantized[row] = emb[idx[row]]
    // 64 rows x 16 float4 = 1024 float4, 4 per thread.
    const float4* emb4 = reinterpret_cast<const float4*>(emb);
    float4* q4 = reinterpret_cast<float4*>(out_q + (size_t)blockIdx.x * ROWS_PB * EMB_DIM);
    #pragma unroll
    for (int i = 0; i < 4; ++i) {
        int e4 = t + i * 256;      // float4 index within this block's 4096-float chunk
        int rr = e4 >> 4;          // row-in-block
        int cc = e4 & 15;          // float4-col
        q4[e4] = emb4[sidx[rr] * 16 + cc];
    }
}

extern "C" void kernel_launch(void* const* d_in, const int* in_sizes, int n_in,
                              void* d_out, int out_size, void* d_ws, size_t ws_size,
                              hipStream_t stream) {
    const float* x   = (const float*)d_in[0];
    const float* emb = (const float*)d_in[1];
    float* out_q   = (float*)d_out;
    float* out_idx = out_q + Q_ELEMS;
    float* sume    = (float*)d_ws;   // 4 KB

    vq_prep<<<dim3(NUM_EMB / 256), dim3(256), 0, stream>>>(emb, sume);
    vq_main<<<dim3(N_ROWS / ROWS_PB), dim3(256), 0, stream>>>(x, emb, sume, out_q, out_idx);
}

// Round 5
// 289.887 us; speedup vs baseline: 3.2915x; 3.2915x over previous
//
#include <hip/hip_runtime.h>

// VQ-VAE quantize, BIT-EXACT replication of the numpy float32 reference:
//   sumx = np.sum(xf*xf, axis=1)   [numpy pairwise_sum, n=64, 8-accumulator order]
//   sume = np.sum(emb*emb, axis=1) [same]
//   M    = (2.0*xf) @ emb.T        [OpenBLAS sgemm: sequential k-order FMA, beta=0]
//   d    = fl32(fl32(sumx + sume) - M);  idx = argmin (first minimum)
//
// R3: 621 us, SGPR=112 (emb via s_load), occupancy 23.7%, VALU 39% -> latency-bound.
// R4: k-split x4 raised occupancy to 52% BUT seg=t>>6 broke provable wave-uniformity
//     of the emb address -> SGPR=32, per-lane global_load_dword, VALU 26%, 1005 us.
// R5: same structure as R4 + readfirstlane(seg) -> kbeg in SGPR -> s_load restored
//     AND 52% occupancy kept. Numerics identical (same FMA order, ascending-seg
//     first-min combine).

#define N_ROWS   131072
#define NUM_EMB  1024
#define EMB_DIM  64
#define Q_ELEMS  8388608
#define KSEG     256          // k per wave-segment
#define ROWS_PB  64           // rows per block

// numpy pairwise_sum (n=64, contiguous) of fl32(a[i]*a[i]).
__device__ __forceinline__ float np_pairwise_sq64(const float* a) {
    #pragma clang fp contract(off)
    float r0 = a[0]*a[0], r1 = a[1]*a[1], r2 = a[2]*a[2], r3 = a[3]*a[3];
    float r4 = a[4]*a[4], r5 = a[5]*a[5], r6 = a[6]*a[6], r7 = a[7]*a[7];
    #pragma unroll
    for (int i = 8; i < 64; i += 8) {
        r0 += a[i+0]*a[i+0];
        r1 += a[i+1]*a[i+1];
        r2 += a[i+2]*a[i+2];
        r3 += a[i+3]*a[i+3];
        r4 += a[i+4]*a[i+4];
        r5 += a[i+5]*a[i+5];
        r6 += a[i+6]*a[i+6];
        r7 += a[i+7]*a[i+7];
    }
    return ((r0 + r1) + (r2 + r3)) + ((r4 + r5) + (r6 + r7));
}

__global__ __launch_bounds__(256) void vq_prep(const float* __restrict__ emb,
                                               float* __restrict__ sume) {
    int k = blockIdx.x * 256 + threadIdx.x;
    if (k < NUM_EMB) {
        sume[k] = np_pairwise_sq64(emb + (k << 6));
    }
}

__global__ __launch_bounds__(256) void vq_main(const float* __restrict__ x,
                                               const float* __restrict__ emb,
                                               const float* __restrict__ sume,
                                               float* __restrict__ out_q,
                                               float* __restrict__ out_idx) {
    const int t   = threadIdx.x;
    // seg is constant across each 64-lane wave; readfirstlane materializes it in an
    // SGPR so the emb/sume addresses below are provably uniform -> s_load path.
    const int seg  = __builtin_amdgcn_readfirstlane(t >> 6);
    const int r    = t & 63;            // row within block
    const int row  = blockIdx.x * ROWS_PB + r;
    const int kbeg = seg * KSEG;        // SGPR

    // Load this thread's 64-float row into registers (4 segs share a row -> L1 hits).
    float rx[EMB_DIM];
    const float4* xr = reinterpret_cast<const float4*>(x + (size_t)row * EMB_DIM);
    #pragma unroll
    for (int j = 0; j < 16; ++j) {
        float4 v = xr[j];
        rx[4*j+0] = v.x; rx[4*j+1] = v.y; rx[4*j+2] = v.z; rx[4*j+3] = v.w;
    }

    // numpy-order fl32 sum of squares, then scale row by 2 (exact, matches 2.0*xf).
    const float sumx = np_pairwise_sq64(rx);
    #pragma unroll
    for (int i = 0; i < EMB_DIM; ++i) rx[i] *= 2.0f;

    float m = 3.4e38f;
    int   b = 0;

    // Segment k-loop: sgemm-order sequential-k FMA, 2 independent chains for ILP.
    // e0 address is SGPR-based + loop-uniform offset -> s_load (scalar pipe).
    for (int k = kbeg; k < kbeg + KSEG; k += 2) {
        const float* __restrict__ e0 = emb + (k << 6);
        float c0 = 0.0f, c1 = 0.0f;
        #pragma unroll
        for (int i = 0; i < EMB_DIM; ++i) {
            c0 = fmaf(rx[i], e0[i],      c0);
            c1 = fmaf(rx[i], e0[64 + i], c1);
        }
        {
            #pragma clang fp contract(off)
            float t0 = sumx + sume[k];     // fl32 add at magnitude ~64
            float d0 = t0 - c0;            // fl32 sub -> the decisive grid rounding
            float t1 = sumx + sume[k + 1];
            float d1 = t1 - c1;
            if (d0 < m) { m = d0; b = k; }     // strict < => first-min (np.argmin)
            if (d1 < m) { m = d1; b = k + 1; }
        }
    }

    // Combine the 4 segment-partials per row: ascending seg, strict < keeps the
    // lowest-k winner on ties -> exact np.argmin first-min semantics.
    __shared__ float lm[4][ROWS_PB];
    __shared__ int   lb[4][ROWS_PB];
    __shared__ int   sidx[ROWS_PB];
    lm[seg][r] = m;
    lb[seg][r] = b;
    __syncthreads();
    if (t < ROWS_PB) {
        float bm = lm[0][t]; int bb = lb[0][t];
        #pragma unroll
        for (int s = 1; s < 4; ++s) {
            float sm = lm[s][t];
            if (sm < bm) { bm = sm; bb = lb[s][t]; }
        }
        out_idx[blockIdx.x * ROWS_PB + t] = (float)bb;
        sidx[t] = bb;
    }
    __syncthreads();

    // Cooperative coalesced gather: quantized[row] = emb[idx[row]]
    // 64 rows x 16 float4 = 1024 float4, 4 per thread.
    const float4* emb4 = reinterpret_cast<const float4*>(emb);
    float4* q4 = reinterpret_cast<float4*>(out_q + (size_t)blockIdx.x * ROWS_PB * EMB_DIM);
    #pragma unroll
    for (int i = 0; i < 4; ++i) {
        int e4 = t + i * 256;      // float4 index within this block's 4096-float chunk
        int rr = e4 >> 4;          // row-in-block
        int cc = e4 & 15;          // float4-col
        q4[e4] = emb4[sidx[rr] * 16 + cc];
    }
}

extern "C" void kernel_launch(void* const* d_in, const int* in_sizes, int n_in,
                              void* d_out, int out_size, void* d_ws, size_t ws_size,
                              hipStream_t stream) {
    const float* x   = (const float*)d_in[0];
    const float* emb = (const float*)d_in[1];
    float* out_q   = (float*)d_out;
    float* out_idx = out_q + Q_ELEMS;
    float* sume    = (float*)d_ws;   // 4 KB

    vq_prep<<<dim3(NUM_EMB / 256), dim3(256), 0, stream>>>(emb, sume);
    vq_main<<<dim3(N_ROWS / ROWS_PB), dim3(256), 0, stream>>>(x, emb, sume, out_q, out_idx);
}

// Round 6
// 226.904 us; speedup vs baseline: 4.2052x; 1.2776x over previous
//
#include <hip/hip_runtime.h>

// VQ-VAE quantize, BIT-EXACT replication of the numpy float32 reference:
//   sumx = np.sum(xf*xf, axis=1)   [numpy pairwise_sum, n=64, 8-accumulator order]
//   sume = np.sum(emb*emb, axis=1) [same]
//   M    = (2.0*xf) @ emb.T        [OpenBLAS sgemm: sequential k-order FMA, beta=0]
//   d    = fl32(fl32(sumx + sume) - M);  idx = argmin (first minimum)
//
// R3: 621 us — s_load path, occupancy 23.7% (grid-limited), VALU 39%.
// R4: 1005 us — k-split raised occupancy but seg=t>>6 killed s_load (SGPR 32).
// R5: 290 us — readfirstlane(seg) restored s_load + 45.8% occupancy, VALU 79%.
// R6: 2 rows/thread: e-operands are per-WAVE (SGPR broadcast), so doubling
//     rows doubles FMA per s_load window (256->512 cyc coverage per k-pair).
//     VGPR ~150 -> 3 waves/SIMD; net latency-coverage +60%.

#define N_ROWS   131072
#define NUM_EMB  1024
#define EMB_DIM  64
#define Q_ELEMS  8388608
#define KSEG     256          // k per wave-segment
#define ROWS_PB  128          // rows per block (2 per thread)

// numpy pairwise_sum (n=64, contiguous) of fl32(a[i]*a[i]).
__device__ __forceinline__ float np_pairwise_sq64(const float* a) {
    #pragma clang fp contract(off)
    float r0 = a[0]*a[0], r1 = a[1]*a[1], r2 = a[2]*a[2], r3 = a[3]*a[3];
    float r4 = a[4]*a[4], r5 = a[5]*a[5], r6 = a[6]*a[6], r7 = a[7]*a[7];
    #pragma unroll
    for (int i = 8; i < 64; i += 8) {
        r0 += a[i+0]*a[i+0];
        r1 += a[i+1]*a[i+1];
        r2 += a[i+2]*a[i+2];
        r3 += a[i+3]*a[i+3];
        r4 += a[i+4]*a[i+4];
        r5 += a[i+5]*a[i+5];
        r6 += a[i+6]*a[i+6];
        r7 += a[i+7]*a[i+7];
    }
    return ((r0 + r1) + (r2 + r3)) + ((r4 + r5) + (r6 + r7));
}

__global__ __launch_bounds__(256) void vq_prep(const float* __restrict__ emb,
                                               float* __restrict__ sume) {
    int k = blockIdx.x * 256 + threadIdx.x;
    if (k < NUM_EMB) {
        sume[k] = np_pairwise_sq64(emb + (k << 6));
    }
}

__global__ __launch_bounds__(256) void vq_main(const float* __restrict__ x,
                                               const float* __restrict__ emb,
                                               const float* __restrict__ sume,
                                               float* __restrict__ out_q,
                                               float* __restrict__ out_idx) {
    const int t = threadIdx.x;
    // seg is constant across each 64-lane wave; readfirstlane pins it in an SGPR
    // so emb/sume addresses are provably uniform -> scalar-load path (R5 lesson).
    const int seg  = __builtin_amdgcn_readfirstlane(t >> 6);
    const int r    = t & 63;
    const int row0 = blockIdx.x * ROWS_PB + r;        // this thread's two rows
    const int kbeg = seg * KSEG;                      // SGPR

    // Load both 64-float rows into registers.
    float rx0[EMB_DIM], rx1[EMB_DIM];
    {
        const float4* xr0 = reinterpret_cast<const float4*>(x + (size_t)row0 * EMB_DIM);
        const float4* xr1 = reinterpret_cast<const float4*>(x + (size_t)(row0 + 64) * EMB_DIM);
        #pragma unroll
        for (int j = 0; j < 16; ++j) {
            float4 v0 = xr0[j];
            rx0[4*j+0] = v0.x; rx0[4*j+1] = v0.y; rx0[4*j+2] = v0.z; rx0[4*j+3] = v0.w;
            float4 v1 = xr1[j];
            rx1[4*j+0] = v1.x; rx1[4*j+1] = v1.y; rx1[4*j+2] = v1.z; rx1[4*j+3] = v1.w;
        }
    }

    // numpy-order fl32 sum of squares, then scale rows by 2 (exact, = 2.0*xf).
    const float sumx0 = np_pairwise_sq64(rx0);
    const float sumx1 = np_pairwise_sq64(rx1);
    #pragma unroll
    for (int i = 0; i < EMB_DIM; ++i) { rx0[i] *= 2.0f; rx1[i] *= 2.0f; }

    float m0 = 3.4e38f, m1 = 3.4e38f;
    int   b0 = 0,       b1 = 0;

    // Segment k-loop: sgemm-order sequential-k FMA. 4 independent chains
    // (2 rows x 2 k) share each wave-uniform e-fetch; per-chain i-order exact.
    for (int k = kbeg; k < kbeg + KSEG; k += 2) {
        const float* __restrict__ e0 = emb + (k << 6);   // SGPR address -> s_load
        float c00 = 0.0f, c01 = 0.0f, c10 = 0.0f, c11 = 0.0f;
        #pragma unroll
        for (int i = 0; i < EMB_DIM; ++i) {
            float ea = e0[i], eb = e0[64 + i];
            c00 = fmaf(rx0[i], ea, c00);
            c01 = fmaf(rx0[i], eb, c01);
            c10 = fmaf(rx1[i], ea, c10);
            c11 = fmaf(rx1[i], eb, c11);
        }
        {
            #pragma clang fp contract(off)
            float sk0 = sume[k], sk1 = sume[k + 1];
            float d00 = (sumx0 + sk0) - c00;   // fl32 grid rounding at ~64
            float d01 = (sumx0 + sk1) - c01;
            float d10 = (sumx1 + sk0) - c10;
            float d11 = (sumx1 + sk1) - c11;
            if (d00 < m0) { m0 = d00; b0 = k; }     // strict < => np first-min
            if (d01 < m0) { m0 = d01; b0 = k + 1; }
            if (d10 < m1) { m1 = d10; b1 = k; }
            if (d11 < m1) { m1 = d11; b1 = k + 1; }
        }
    }

    // Combine 4 segment-partials per row: ascending seg + strict < keeps the
    // lowest-k winner on ties -> exact np.argmin first-min semantics.
    __shared__ float lm[4][ROWS_PB];
    __shared__ int   lb[4][ROWS_PB];
    __shared__ int   sidx[ROWS_PB];
    lm[seg][r]      = m0;  lb[seg][r]      = b0;
    lm[seg][r + 64] = m1;  lb[seg][r + 64] = b1;
    __syncthreads();
    if (t < ROWS_PB) {
        float bm = lm[0][t]; int bb = lb[0][t];
        #pragma unroll
        for (int s = 1; s < 4; ++s) {
            float sm = lm[s][t];
            if (sm < bm) { bm = sm; bb = lb[s][t]; }
        }
        out_idx[blockIdx.x * ROWS_PB + t] = (float)bb;
        sidx[t] = bb;
    }
    __syncthreads();

    // Cooperative coalesced gather: quantized[row] = emb[idx[row]]
    // 128 rows x 16 float4 = 2048 float4, 8 per thread.
    const float4* emb4 = reinterpret_cast<const float4*>(emb);
    float4* q4 = reinterpret_cast<float4*>(out_q + (size_t)blockIdx.x * ROWS_PB * EMB_DIM);
    #pragma unroll
    for (int i = 0; i < 8; ++i) {
        int e4 = t + i * 256;      // float4 index within this block's 8192-float chunk
        int rr = e4 >> 4;          // row-in-block
        int cc = e4 & 15;          // float4-col
        q4[e4] = emb4[sidx[rr] * 16 + cc];
    }
}

extern "C" void kernel_launch(void* const* d_in, const int* in_sizes, int n_in,
                              void* d_out, int out_size, void* d_ws, size_t ws_size,
                              hipStream_t stream) {
    const float* x   = (const float*)d_in[0];
    const float* emb = (const float*)d_in[1];
    float* out_q   = (float*)d_out;
    float* out_idx = out_q + Q_ELEMS;
    float* sume    = (float*)d_ws;   // 4 KB

    vq_prep<<<dim3(NUM_EMB / 256), dim3(256), 0, stream>>>(emb, sume);
    vq_main<<<dim3(N_ROWS / ROWS_PB), dim3(256), 0, stream>>>(x, emb, sume, out_q, out_idx);
}